// Round 8
// baseline (199.517 us; speedup 1.0000x reference)
//
#include <hip/hip_runtime.h>
#include <hip/hip_bf16.h>
#include <math.h>

#define N_TOK 8192
#define DM 1024
#define KD 64
#define ODIM 1024
#define LOG2E 1.4426950408889634f

typedef unsigned short ushort_t;
typedef __attribute__((ext_vector_type(8))) short short8;
typedef __attribute__((ext_vector_type(4))) float f32x4;

#define MFMA16(a, b, c) __builtin_amdgcn_mfma_f32_16x16x32_bf16((a), (b), (c), 0, 0, 0)

__device__ __forceinline__ float ex2(float x) {
#if __has_builtin(__builtin_amdgcn_exp2f)
    return __builtin_amdgcn_exp2f(x);
#else
    return exp2f(x);
#endif
}
// RNE float->bf16 (finite inputs)
__device__ __forceinline__ ushort_t rne(float x) {
    unsigned u = __float_as_uint(x);
    u += 0x7fffu + ((u >> 16) & 1u);
    return (ushort_t)(u >> 16);
}
__device__ __forceinline__ float ubf(ushort_t h) {
    return __uint_as_float(((unsigned)h) << 16);
}
__device__ __forceinline__ void split2(float x, ushort_t& hi, ushort_t& lo) {
    hi = rne(x);
    lo = rne(x - ubf(hi));
}
__device__ __forceinline__ unsigned bfpack(float a, float b) {
    unsigned ua = __float_as_uint(a); ua += 0x7fffu + ((ua >> 16) & 1u);
    unsigned ub = __float_as_uint(b); ub += 0x7fffu + ((ub >> 16) & 1u);
    return (ua >> 16) | (ub & 0xffff0000u);
}
// async global->LDS, 16B per lane; lds dst must be wave-uniform base (+lane*16 implicit)
__device__ __forceinline__ void gld_lds16(const void* g, void* l) {
    __builtin_amdgcn_global_load_lds(
        (const __attribute__((address_space(1))) unsigned int*)g,
        (__attribute__((address_space(3))) unsigned int*)l, 16, 0, 0);
}

// ---------------- Kernel 0: weight transpose + x hi/lo pre-split ----------------
// grid 5120 x 256. idx<192K: w_qkv transpose+split; <256K: w_out; rest: x
// pre-split (8 elems/thread) so qkv's inner loop has NO VALU conversion chain.
__global__ __launch_bounds__(256) void prep_kernel(
    const float* __restrict__ wq, const float* __restrict__ wo,
    const float* __restrict__ x,
    ushort_t* __restrict__ wT_hi, ushort_t* __restrict__ wT_lo,
    ushort_t* __restrict__ woT_hi, ushort_t* __restrict__ woT_lo,
    ushort_t* __restrict__ x_hi, ushort_t* __restrict__ x_lo)
{
    const int idx = blockIdx.x * 256 + threadIdx.x;
    if (idx < 192 * 1024) {
        const int c = idx >> 10, k = idx & 1023;
        ushort_t h, l; split2(wq[k * 192 + c], h, l);
        wT_hi[idx] = h; wT_lo[idx] = l;
    } else if (idx < 256 * 1024) {
        const int j = idx - 192 * 1024;
        const int c = j >> 6, k = j & 63;
        ushort_t h, l; split2(wo[k * ODIM + c], h, l);
        woT_hi[j] = h; woT_lo[j] = l;
    } else {
        const size_t j = (size_t)(idx - 256 * 1024) * 8;   // 1M threads x 8 elems
        const float4 xa = *(const float4*)&x[j];
        const float4 xb = *(const float4*)&x[j + 4];
        const float xe[8] = {xa.x, xa.y, xa.z, xa.w, xb.x, xb.y, xb.z, xb.w};
        union { short8 v; ushort_t u[8]; } hh, ll;
#pragma unroll
        for (int e = 0; e < 8; ++e) { split2(xe[e], hh.u[e], ll.u[e]); }
        *(short8*)&x_hi[j] = hh.v;
        *(short8*)&x_lo[j] = ll.v;
    }
}

// ---------------- Kernel 1: LDS-pipelined QKV projection GEMM ----------------
// grid 256 x 256. Block = 64 rows (R0 = (bb>>1)*64) x 96-col half (h = bb&1);
// 4 waves in 2x2 grid, wave tile 32 rows x 48 cols. Round-4 lesson: register
// pipelines get un-rolled by the compiler (VGPR 28!) -> use the attn-proven
// schedule the compiler CANNOT undo: global_load_lds DMA (no VGPR), counted
// vmcnt asm, double-buffered LDS, 2 barriers/step.
__global__ __launch_bounds__(256) void qkv_kernel(
    const ushort_t* __restrict__ x_hi, const ushort_t* __restrict__ x_lo,
    const ushort_t* __restrict__ wT_hi, const ushort_t* __restrict__ wT_lo,
    const float* __restrict__ b,
    ushort_t* __restrict__ q_hi, ushort_t* __restrict__ q_lo,
    ushort_t* __restrict__ k_hi, ushort_t* __restrict__ k_lo,
    ushort_t* __restrict__ vT)
{
    // per buf (20480 ushorts = 40KB): Xh [0,4096) Xl [4096,8192)
    //                                 Wh [8192,14336) Wl [14336,20480)
    __shared__ ushort_t S[2][20480];   // 80 KB total

    const int tid = threadIdx.x;
    const int wv = tid >> 6, lane = tid & 63, g = lane >> 4, i = lane & 15;
    const int bb = (int)blockIdx.x;
    const int R0 = (bb >> 1) * 64, h = bb & 1;
    const int rh = wv >> 1, cq = wv & 1;
    const int sub = lane >> 3, s = lane & 7;
    const f32x4 zero4 = {0.f, 0.f, 0.f, 0.f};

    auto stage = [&](int buf, int t) {
        const int kb = t * 64;
#pragma unroll
        for (int j = 0; j < 10; ++j) {
            const int c = wv + 4 * j;
            ushort_t* dst = &S[buf][c << 9];
            const ushort_t* src;
            if (j < 4) {
                const int r = ((c & 7) << 3) + sub;            // 0..63
                src = (j < 2 ? x_hi : x_lo) +
                      (size_t)(R0 + r) * DM + kb + ((s ^ (r & 7)) << 3);
            } else if (j < 7) {
                const int wc = ((c - 16) << 3) + sub;          // 0..95
                src = wT_hi + (size_t)(h * 96 + wc) * DM + kb + ((s ^ (wc & 7)) << 3);
            } else {
                const int wc = ((c - 28) << 3) + sub;          // 0..95
                src = wT_lo + (size_t)(h * 96 + wc) * DM + kb + ((s ^ (wc & 7)) << 3);
            }
            gld_lds16(src, dst);
        }
    };

    f32x4 acc[2][3] = {{zero4, zero4, zero4}, {zero4, zero4, zero4}};

    stage(0, 0);   // prologue: 10 DMA issues/wave

    for (int t = 0; t < 16; ++t) {
        const int cur = t & 1;
        if (t + 1 < 16) {
            stage(cur ^ 1, t + 1);                            // next step in flight
            asm volatile("s_waitcnt vmcnt(10)" ::: "memory"); // own step-t DMAs done
        } else {
            asm volatile("s_waitcnt vmcnt(0)" ::: "memory");
        }
        __builtin_amdgcn_s_barrier();   // step t staged by all 4 waves

        const ushort_t* Sb = S[cur];
        short8 ah[2][2], al[2][2], bh[3][2], bl[3][2];
#pragma unroll
        for (int a = 0; a < 2; ++a) {
            const int r = (rh << 5) + (a << 4) + i;
#pragma unroll
            for (int kf = 0; kf < 2; ++kf) {
                const int off = (r << 6) + (((g + (kf << 2)) ^ (r & 7)) << 3);
                ah[a][kf] = *(const short8*)&Sb[off];
                al[a][kf] = *(const short8*)&Sb[4096 + off];
            }
        }
#pragma unroll
        for (int ct = 0; ct < 3; ++ct) {
            const int wc = cq * 48 + (ct << 4) + i;
#pragma unroll
            for (int kf = 0; kf < 2; ++kf) {
                const int off = (wc << 6) + (((g + (kf << 2)) ^ (wc & 7)) << 3);
                bh[ct][kf] = *(const short8*)&Sb[8192 + off];
                bl[ct][kf] = *(const short8*)&Sb[14336 + off];
            }
        }
#pragma unroll
        for (int a = 0; a < 2; ++a)
#pragma unroll
            for (int ct = 0; ct < 3; ++ct) {
                f32x4 v = acc[a][ct];
                v = MFMA16(ah[a][0], bh[ct][0], v);
                v = MFMA16(ah[a][1], bh[ct][1], v);
                v = MFMA16(ah[a][0], bl[ct][0], v);
                v = MFMA16(ah[a][1], bl[ct][1], v);
                v = MFMA16(al[a][0], bh[ct][0], v);
                v = MFMA16(al[a][1], bh[ct][1], v);
                acc[a][ct] = v;
            }
        // my LDS reads landed in regs -> safe for others to overwrite buf
        asm volatile("s_waitcnt lgkmcnt(0)" ::: "memory");
        __builtin_amdgcn_s_barrier();
    }

    // epilogue: wave tile = rows R0+rh*32 .. +31, ctids h*6+cq*3 .. +2
#pragma unroll
    for (int ct = 0; ct < 3; ++ct) {
        const int ctid = h * 6 + cq * 3 + ct;
        const int col = (ctid << 4) + i;
        const float bias = b[col];
#pragma unroll
        for (int a = 0; a < 2; ++a) {
            const int row0 = R0 + (rh << 5) + (a << 4) + (g << 2);
            if (ctid < 4) {        // q: pre-scale by log2e
#pragma unroll
                for (int reg = 0; reg < 4; ++reg) {
                    ushort_t hh, ll; split2((acc[a][ct][reg] + bias) * LOG2E, hh, ll);
                    q_hi[(row0 + reg) * KD + col] = hh;
                    q_lo[(row0 + reg) * KD + col] = ll;
                }
            } else if (ctid < 8) { // k
                const int c2 = col - 64;
#pragma unroll
                for (int reg = 0; reg < 4; ++reg) {
                    ushort_t hh, ll; split2(acc[a][ct][reg] + bias, hh, ll);
                    k_hi[(row0 + reg) * KD + c2] = hh;
                    k_lo[(row0 + reg) * KD + c2] = ll;
                }
            } else {               // v -> transposed bf16
                union { ushort_t u[4]; uint2 v; } pk;
#pragma unroll
                for (int reg = 0; reg < 4; ++reg) pk.u[reg] = rne(acc[a][ct][reg] + bias);
                *(uint2*)&vT[(size_t)(col - 128) * N_TOK + row0] = pk.v;
            }
        }
    }
}

// ---------------- Kernel 2: 8-wave/128-row LDS-pipelined causal flash attention ----------------
// Round-7 lesson: 4-wave/64-row blocks gave 2 sequential block generations at
// ~2 blocks/CU resident -> 66% stall. Now: 512 threads, 8 waves, 128 q-rows
// per block; the same 32KB K hi/lo double-buffer serves 2x the q-rows (K DMA
// per wave-tile halves: 2 issues, vmcnt 10/8/2), and active blocks drop to
// 544 = 2.1/CU -> ALL co-resident (~17 waves/CU), one generation.
// Dense causal-active enumeration over 128-row geometry: group a = gb2>>(LC-1)
// has a+1 chunks; CUM = G*a(a+1)/2, G = 1<<(LC-1). Complement appended.
// Causal boundary differs between the block's two 64-row halves: each wave
// clamps to its own t1w; staging/barriers unconditional (shared K), compute
// guarded; vmcnt immediates branch on the wave-uniform active flag so an
// inactive wave still drains its own stage DMAs before the barrier.
__global__ __launch_bounds__(512) void attn_kernel(
    const ushort_t* __restrict__ q_hi, const ushort_t* __restrict__ q_lo,
    const ushort_t* __restrict__ k_hi, const ushort_t* __restrict__ k_lo,
    const ushort_t* __restrict__ vT,
    float* __restrict__ Opart, float* __restrict__ MLpart,
    const int* __restrict__ causal_p, const int LC, const int ACT)
{
    __shared__ ushort_t Kls[2][2][4096];   // [buf][hi/lo][64 keys x 64 dims], 32 KB

    const int tid = threadIdx.x;
    const int wv = tid >> 6, lane = tid & 63, g = lane >> 4, i = lane & 15;
    const int causal = *causal_p;
    const f32x4 zero4 = {0.f, 0.f, 0.f, 0.f};
    const int ibase = ((i >> 2) << 3) + (i & 3);

    const int bb = (int)blockIdx.x;
    const int G = 1 << (LC - 1);
    int gb2, chunk;
    if (bb < ACT) {
        // invert CUM(a) = G*a*(a+1)/2
        int a = (int)(sqrtf((float)(2 * bb) / (float)G + 0.25f) - 0.5f);
        while (a > 0 && G * a * (a + 1) / 2 > bb) --a;
        while (G * (a + 1) * (a + 2) / 2 <= bb) ++a;
        const int r = bb - G * a * (a + 1) / 2;
        const int b2 = r / (a + 1);
        chunk = r - b2 * (a + 1);
        gb2 = G * a + b2;
    } else {
        const int j = bb - ACT;                 // complement pairs
        gb2 = j & 63; chunk = j >> 6;
        if (chunk <= (gb2 >> (LC - 1))) return; // covered by dense part
    }
    const int nktB = causal ? 2 * gb2 + 2 : (N_TOK / 64);   // block (upper half)
    const int t0 = chunk << LC;
    if (t0 >= nktB) return;                     // inactive (causal complement)
    const int tmax = t0 + (1 << LC);
    const int t1 = tmax < nktB ? tmax : nktB;

    const int qt = gb2 * 8 + wv;                // global 16-row tile id (0..511)
    const int R0w = qt << 4;                    // wave's q-row base
    const int myNkt = causal ? (R0w >> 6) + 1 : (N_TOK / 64);
    const int t1w = t1 < myNkt ? t1 : myNkt;    // wave's own clamp

    const short8 qh0 = *(const short8*)&q_hi[(R0w + i) * KD + g * 8];
    const short8 qh1 = *(const short8*)&q_hi[(R0w + i) * KD + 32 + g * 8];
    const short8 ql0 = *(const short8*)&q_lo[(R0w + i) * KD + g * 8];
    const short8 ql1 = *(const short8*)&q_lo[(R0w + i) * KD + 32 + g * 8];

    // stage K hi/lo tile t into buffer nb: wave wv covers 1KB chunk wv of each
    // 8KB matrix (8 waves cover all 64 rows). LDS write linear (HW); global
    // SOURCE slot pre-permuted (rule #21).
    const int srow = lane >> 3;      // row within chunk (0..7)
    const int sslot = lane & 7;      // 16B slot within row
    auto stageK = [&](int nb, int t) {
        const int kb2 = t << 6;
        const int row = (wv << 3) + srow;
        const int sw = ((row & 3) << 1) | ((row >> 3) & 1);
        const size_t src = (size_t)(kb2 + row) * KD + ((sslot ^ sw) << 3);
        gld_lds16(&k_hi[src], &Kls[nb][0][wv << 9]);
        gld_lds16(&k_lo[src], &Kls[nb][1][wv << 9]);
    };

    f32x4 o4[4] = {zero4, zero4, zero4, zero4};
    float runm = -1e30f, runl = 0.f;

    stageK(0, t0);   // prologue: 2 lds-DMA issues/wave

    for (int t = t0; t < t1; ++t) {
        const int cur = (t - t0) & 1;
        const int kb = t << 6;
        const bool more = (t + 1 < t1);
        const bool act = (t < t1w);             // wave-uniform

        // V for current tile: issue now, consume after softmax.
        short8 va0[4], va1[4];
        if (act) {
#pragma unroll
            for (int ct2 = 0; ct2 < 4; ++ct2) {
                const size_t vrow = (size_t)(ct2 * 16 + i) * N_TOK + kb;
                va0[ct2] = *(const short8*)&vT[vrow + g * 8];
                va1[ct2] = *(const short8*)&vT[vrow + 32 + g * 8];
            }
        }
        if (more) {
            stageK(cur ^ 1, t + 1);                           // next tile in flight
            if (act) asm volatile("s_waitcnt vmcnt(10)" ::: "memory"); // 8V+2next left
            else     asm volatile("s_waitcnt vmcnt(2)" ::: "memory");  // own K(cur) done
        } else {
            if (act) asm volatile("s_waitcnt vmcnt(8)" ::: "memory");
            else     asm volatile("s_waitcnt vmcnt(0)" ::: "memory");
        }
        __builtin_amdgcn_s_barrier();   // K(cur) staged by all 8 waves

        if (act) {
            f32x4 s4[4];
#pragma unroll
            for (int ct = 0; ct < 4; ++ct) {
                const int r = ((ct & 1) << 2) + ((ct >> 1) << 5) + ibase;
                const int sw = ((r & 3) << 1) | ((r >> 3) & 1);
                const ushort_t* khp = &Kls[cur][0][r << 6];
                const ushort_t* klp = &Kls[cur][1][r << 6];
                const short8 kh0 = *(const short8*)&khp[(g ^ sw) << 3];
                const short8 kh1 = *(const short8*)&khp[((g + 4) ^ sw) << 3];
                const short8 kl0 = *(const short8*)&klp[(g ^ sw) << 3];
                const short8 kl1 = *(const short8*)&klp[((g + 4) ^ sw) << 3];
                f32x4 a = MFMA16(kh0, qh0, zero4);
                a = MFMA16(kh1, qh1, a);
                a = MFMA16(kh0, ql0, a);
                a = MFMA16(kh1, ql1, a);
                a = MFMA16(kl0, qh0, a);
                a = MFMA16(kl1, qh1, a);
                s4[ct] = a;
            }
            // my LDS reads landed in regs -> safe for others to overwrite buf
            asm volatile("s_waitcnt lgkmcnt(0)" ::: "memory");
            __builtin_amdgcn_s_barrier();

            if (causal && (kb + 64 > R0w)) {  // diagonal tile only
#pragma unroll
                for (int ct = 0; ct < 4; ++ct) {
                    const int kba = kb + ((ct & 1) << 2) + ((ct >> 1) << 5);
#pragma unroll
                    for (int reg = 0; reg < 4; ++reg) {
                        const int key = kba + (g << 3) + reg;
                        s4[ct][reg] = (key <= R0w + i) ? s4[ct][reg] : -1e30f;
                    }
                }
            }
            // online softmax: lane owns qrow i; scalar state; defer-max THR=8
            float mx = -1e30f;
#pragma unroll
            for (int ct = 0; ct < 4; ++ct)
#pragma unroll
                for (int reg = 0; reg < 4; ++reg) mx = fmaxf(mx, s4[ct][reg]);
            mx = fmaxf(mx, __shfl_xor(mx, 16));
            mx = fmaxf(mx, __shfl_xor(mx, 32));
            const bool defer = __all(mx - runm <= 8.0f);
            const float nm = defer ? runm : fmaxf(runm, mx);
            const float al = defer ? 1.0f : ex2(runm - nm);
            runm = nm;
            float rs = 0.f;
#pragma unroll
            for (int ct = 0; ct < 4; ++ct)
#pragma unroll
                for (int reg = 0; reg < 4; ++reg) {
                    const float p = ex2(s4[ct][reg] - nm);
                    s4[ct][reg] = p;
                    rs += p;
                }
            rs += __shfl_xor(rs, 16);
            rs += __shfl_xor(rs, 32);
            runl = runl * al + rs;
            if (!defer) {
#pragma unroll
                for (int ct2 = 0; ct2 < 4; ++ct2)
#pragma unroll
                    for (int reg = 0; reg < 4; ++reg) o4[ct2][reg] *= al;
            }
            // P^T B-frags: pure register repack
            short8 pb0, pb1;
            {
                union { unsigned w[4]; short8 v; } u;
                u.w[0] = bfpack(s4[0][0], s4[0][1]); u.w[1] = bfpack(s4[0][2], s4[0][3]);
                u.w[2] = bfpack(s4[1][0], s4[1][1]); u.w[3] = bfpack(s4[1][2], s4[1][3]);
                pb0 = u.v;
                u.w[0] = bfpack(s4[2][0], s4[2][1]); u.w[1] = bfpack(s4[2][2], s4[2][3]);
                u.w[2] = bfpack(s4[3][0], s4[3][1]); u.w[3] = bfpack(s4[3][2], s4[3][3]);
                pb1 = u.v;
            }
            // V landed (leaves next-tile K stage in flight when more)
            if (more) asm volatile("s_waitcnt vmcnt(2)" ::: "memory");
            else      asm volatile("s_waitcnt vmcnt(0)" ::: "memory");
#pragma unroll
            for (int ct2 = 0; ct2 < 4; ++ct2) {
                o4[ct2] = MFMA16(va0[ct2], pb0, o4[ct2]);
                o4[ct2] = MFMA16(va1[ct2], pb1, o4[ct2]);
            }
        } else {
            // inactive wave: keep barrier structure only
            asm volatile("s_waitcnt lgkmcnt(0)" ::: "memory");
            __builtin_amdgcn_s_barrier();
        }
    }

    // epilogue: each wave owns the full (qt, chunk) partial; layout identical
    // to merge's expectation: pidx = pb(qtile) + 4*chunk
    const int pidx = (((qt >> 2) << (7 - LC)) + chunk) * 4 + (qt & 3);
#pragma unroll
    for (int ct2 = 0; ct2 < 4; ++ct2)
#pragma unroll
        for (int reg = 0; reg < 4; ++reg) {
            const int d = ct2 * 16 + 4 * g + reg;
            Opart[((size_t)pidx * 16 + i) * 64 + d] = o4[ct2][reg];
        }
    if (lane < 16) {
        MLpart[pidx * 32 + lane] = runm;
        MLpart[pidx * 32 + 16 + lane] = runl;
    }
}

// ---------------- Kernel 3a: split-K merge (massively parallel) ----------------
// One thread per (row, d) = 524288 threads = 2048 blocks, zero LDS ->
// ~32 waves/CU; pure TLP hides the load latency, Opart read exactly once.
// Writes normalized bf16 hi/lo ao[8192][64] into the dead q_hi/q_lo region.
__global__ __launch_bounds__(256) void merge_kernel(
    const float* __restrict__ Opart, const float* __restrict__ MLpart,
    ushort_t* __restrict__ aoh, ushort_t* __restrict__ aol,
    const int* __restrict__ causal_p, const int LC)
{
    const int idx = blockIdx.x * 256 + threadIdx.x;
    const int d = idx & 63, row = idx >> 6;               // row 0..8191
    const int r = row & 15, qtile = row >> 4, gb = row >> 6;
    const int causal = *causal_p;
    const int nkt = causal ? gb + 1 : (N_TOK / 64);
    const int nch = (nkt + (1 << LC) - 1) >> LC;          // 1..16
    const int pb = ((gb << (7 - LC)) << 2) + (qtile & 3); // pidx(c) = pb + 4c
    float m[16], l[16];
#pragma unroll
    for (int c = 0; c < 16; ++c) {
        if (c < nch) {
            m[c] = MLpart[(pb + 4 * c) * 32 + r];
            l[c] = MLpart[(pb + 4 * c) * 32 + 16 + r];
        } else { m[c] = -1e30f; l[c] = 0.f; }
    }
    float M = m[0];
#pragma unroll
    for (int c = 1; c < 16; ++c) M = fmaxf(M, m[c]);
    float den = 0.f, O = 0.f;
#pragma unroll
    for (int c = 0; c < 16; ++c) {
        const float e = ex2(m[c] - M);
        den += l[c] * e;
        if (c < nch)
            O += Opart[((size_t)(pb + 4 * c) * 16 + r) * 64 + d] * e;
    }
    ushort_t h, lo2; split2(O / den, h, lo2);
    aoh[row * 64 + d] = h;
    aol[row * 64 + d] = lo2;
}

// ---------------- Kernel 3b: output projection (pure GEMM) ----------------
// grid 2048 x 256. Block (qtile=b>>2, qa=b&3): A-frags direct from global ao
// (2MB, L2-resident, 4x reuse), no LDS/sync; MFMA project col quarter qa.
__global__ __launch_bounds__(256) void proj_kernel(
    const ushort_t* __restrict__ aoh, const ushort_t* __restrict__ aol,
    const ushort_t* __restrict__ woT_hi, const ushort_t* __restrict__ woT_lo,
    const float* __restrict__ bo, float* __restrict__ out)
{
    const int tid = threadIdx.x;
    const int wv = tid >> 6, lane = tid & 63, g = lane >> 4, i = lane & 15;
    const int bb = (int)blockIdx.x;
    const int qtile = bb >> 2, qa = bb & 3;
    const int R0 = qtile << 4;
    const f32x4 zero4 = {0.f, 0.f, 0.f, 0.f};
    const short8 ah0 = *(const short8*)&aoh[(R0 + i) * 64 + g * 8];
    const short8 ah1 = *(const short8*)&aoh[(R0 + i) * 64 + 32 + g * 8];
    const short8 al0 = *(const short8*)&aol[(R0 + i) * 64 + g * 8];
    const short8 al1 = *(const short8*)&aol[(R0 + i) * 64 + 32 + g * 8];
#pragma unroll
    for (int cc = 0; cc < 4; ++cc) {
        const int col = (qa << 8) + ((wv << 2) + cc) * 16 + i;
        const short8 bh0 = *(const short8*)&woT_hi[col * KD + g * 8];
        const short8 bh1 = *(const short8*)&woT_hi[col * KD + 32 + g * 8];
        const short8 bl0 = *(const short8*)&woT_lo[col * KD + g * 8];
        const short8 bl1 = *(const short8*)&woT_lo[col * KD + 32 + g * 8];
        f32x4 acc = MFMA16(ah0, bh0, zero4);
        acc = MFMA16(ah1, bh1, acc);
        acc = MFMA16(ah0, bl0, acc);
        acc = MFMA16(ah1, bl1, acc);
        acc = MFMA16(al0, bh0, acc);
        acc = MFMA16(al1, bh1, acc);
        const float bias = bo[col];
#pragma unroll
        for (int reg = 0; reg < 4; ++reg)
            out[(size_t)(R0 + 4 * g + reg) * ODIM + col] = acc[reg] + bias;
    }
}

extern "C" void kernel_launch(void* const* d_in, const int* in_sizes, int n_in,
                              void* d_out, int out_size, void* d_ws, size_t ws_size,
                              hipStream_t stream) {
    const float* x     = (const float*)d_in[0];
    const float* w_qkv = (const float*)d_in[1];
    const float* b_qkv = (const float*)d_in[2];
    const float* w_out = (const float*)d_in[3];
    const float* b_out = (const float*)d_in[4];
    const int* causal  = (const int*)d_in[5];
    float* out         = (float*)d_out;

    // Chunk size: 8 K-tiles (LC=3) needs 39 MB workspace; fall back to 16
    // (LC=4, 23 MB) if the workspace is tight.
    const int LC  = (ws_size >= ((size_t)39 << 20)) ? 3 : 4;
    const int NCH = 128 >> LC;                 // max chunks per gb (64-row units)
    const int G   = 1 << (LC - 1);             // 128-row rows per dense group
    const int NA2 = 64 / G;                    // dense groups
    const int ACT = G * NA2 * (NA2 + 1) / 2;   // causal-active 128-row blocks (544/288)
    const size_t opart_bytes = (size_t)128 * NCH * 4 * 16 * 64 * 4;  // 32 or 16 MB

    char* ws = (char*)d_ws;
    ushort_t* wT_hi  = (ushort_t*)(ws);                    // 384 KB
    ushort_t* wT_lo  = (ushort_t*)(ws + 393216);           // 384 KB
    ushort_t* woT_hi = (ushort_t*)(ws + 786432);           // 128 KB
    ushort_t* woT_lo = (ushort_t*)(ws + 917504);           // 128 KB -> 1 MB
    ushort_t* q_hi   = (ushort_t*)(ws + (1u << 20));
    ushort_t* q_lo   = (ushort_t*)(ws + (2u << 20));
    ushort_t* k_hi   = (ushort_t*)(ws + (3u << 20));
    ushort_t* k_lo   = (ushort_t*)(ws + (4u << 20));
    ushort_t* vT     = (ushort_t*)(ws + (5u << 20));       // -> 6 MB
    // x_hi/x_lo [6MB..38MB) are consumed by qkv BEFORE attn writes
    // Opart/MLpart (same region) -> temporal overlap is safe (in-order stream).
    ushort_t* x_hi   = (ushort_t*)(ws + (6u << 20));       // 16 MB
    ushort_t* x_lo   = (ushort_t*)(ws + (22u << 20));      // 16 MB -> 38 MB
    float*    Opart  = (float*)(ws + (6u << 20));          // 32/16 MB (after qkv)
    float*    MLpart = (float*)(ws + (6u << 20) + opart_bytes);  // 1/0.5 MB
    // ao (merged, normalized bf16 hi/lo, 1 MB each) overlays the dead q_hi /
    // q_lo regions (q consumed by attn; in-order stream -> safe).
    ushort_t* aoh    = (ushort_t*)(ws + (1u << 20));
    ushort_t* aol    = (ushort_t*)(ws + (2u << 20));

    prep_kernel<<<5120, 256, 0, stream>>>(w_qkv, w_out, x, wT_hi, wT_lo,
                                          woT_hi, woT_lo, x_hi, x_lo);
    qkv_kernel<<<256, 256, 0, stream>>>(x_hi, x_lo, wT_hi, wT_lo, b_qkv,
                                        q_hi, q_lo, k_hi, k_lo, vT);
    attn_kernel<<<ACT + 64 * (128 >> LC), 512, 0, stream>>>(
        q_hi, q_lo, k_hi, k_lo, vT, Opart, MLpart, causal, LC, ACT);
    merge_kernel<<<2048, 256, 0, stream>>>(Opart, MLpart, aoh, aol, causal, LC);
    proj_kernel<<<2048, 256, 0, stream>>>(aoh, aol, woT_hi, woT_lo, b_out, out);
}

// Round 9
// 174.502 us; speedup vs baseline: 1.1433x; 1.1433x over previous
//
#include <hip/hip_runtime.h>
#include <hip/hip_bf16.h>
#include <math.h>

#define N_TOK 8192
#define DM 1024
#define KD 64
#define ODIM 1024
#define LOG2E 1.4426950408889634f

typedef unsigned short ushort_t;
typedef __attribute__((ext_vector_type(8))) short short8;
typedef __attribute__((ext_vector_type(4))) float f32x4;

#define MFMA16(a, b, c) __builtin_amdgcn_mfma_f32_16x16x32_bf16((a), (b), (c), 0, 0, 0)

__device__ __forceinline__ float ex2(float x) {
#if __has_builtin(__builtin_amdgcn_exp2f)
    return __builtin_amdgcn_exp2f(x);
#else
    return exp2f(x);
#endif
}
// RNE float->bf16 (finite inputs)
__device__ __forceinline__ ushort_t rne(float x) {
    unsigned u = __float_as_uint(x);
    u += 0x7fffu + ((u >> 16) & 1u);
    return (ushort_t)(u >> 16);
}
__device__ __forceinline__ float ubf(ushort_t h) {
    return __uint_as_float(((unsigned)h) << 16);
}
__device__ __forceinline__ void split2(float x, ushort_t& hi, ushort_t& lo) {
    hi = rne(x);
    lo = rne(x - ubf(hi));
}
__device__ __forceinline__ unsigned bfpack(float a, float b) {
    unsigned ua = __float_as_uint(a); ua += 0x7fffu + ((ua >> 16) & 1u);
    unsigned ub = __float_as_uint(b); ub += 0x7fffu + ((ub >> 16) & 1u);
    return (ua >> 16) | (ub & 0xffff0000u);
}
// async global->LDS, 16B per lane; lds dst must be wave-uniform base (+lane*16 implicit)
__device__ __forceinline__ void gld_lds16(const void* g, void* l) {
    __builtin_amdgcn_global_load_lds(
        (const __attribute__((address_space(1))) unsigned int*)g,
        (__attribute__((address_space(3))) unsigned int*)l, 16, 0, 0);
}

// ---------------- Kernel 0: weight transpose + x hi/lo pre-split ----------------
// grid 5120 x 256. idx<192K: w_qkv transpose+split; <256K: w_out; rest: x
// pre-split (8 elems/thread) so qkv's inner loop has NO VALU conversion chain.
__global__ __launch_bounds__(256) void prep_kernel(
    const float* __restrict__ wq, const float* __restrict__ wo,
    const float* __restrict__ x,
    ushort_t* __restrict__ wT_hi, ushort_t* __restrict__ wT_lo,
    ushort_t* __restrict__ woT_hi, ushort_t* __restrict__ woT_lo,
    ushort_t* __restrict__ x_hi, ushort_t* __restrict__ x_lo)
{
    const int idx = blockIdx.x * 256 + threadIdx.x;
    if (idx < 192 * 1024) {
        const int c = idx >> 10, k = idx & 1023;
        ushort_t h, l; split2(wq[k * 192 + c], h, l);
        wT_hi[idx] = h; wT_lo[idx] = l;
    } else if (idx < 256 * 1024) {
        const int j = idx - 192 * 1024;
        const int c = j >> 6, k = j & 63;
        ushort_t h, l; split2(wo[k * ODIM + c], h, l);
        woT_hi[j] = h; woT_lo[j] = l;
    } else {
        const size_t j = (size_t)(idx - 256 * 1024) * 8;   // 1M threads x 8 elems
        const float4 xa = *(const float4*)&x[j];
        const float4 xb = *(const float4*)&x[j + 4];
        const float xe[8] = {xa.x, xa.y, xa.z, xa.w, xb.x, xb.y, xb.z, xb.w};
        union { short8 v; ushort_t u[8]; } hh, ll;
#pragma unroll
        for (int e = 0; e < 8; ++e) { split2(xe[e], hh.u[e], ll.u[e]); }
        *(short8*)&x_hi[j] = hh.v;
        *(short8*)&x_lo[j] = ll.v;
    }
}

// ---------------- Kernel 1: LDS-pipelined QKV projection GEMM ----------------
// grid 256 x 256. Block = 64 rows (R0 = (bb>>1)*64) x 96-col half (h = bb&1);
// 4 waves in 2x2 grid, wave tile 32 rows x 48 cols. Round-4 lesson: register
// pipelines get un-rolled by the compiler (VGPR 28!) -> use the attn-proven
// schedule the compiler CANNOT undo: global_load_lds DMA (no VGPR), counted
// vmcnt asm, double-buffered LDS, 2 barriers/step.
__global__ __launch_bounds__(256) void qkv_kernel(
    const ushort_t* __restrict__ x_hi, const ushort_t* __restrict__ x_lo,
    const ushort_t* __restrict__ wT_hi, const ushort_t* __restrict__ wT_lo,
    const float* __restrict__ b,
    ushort_t* __restrict__ q_hi, ushort_t* __restrict__ q_lo,
    ushort_t* __restrict__ k_hi, ushort_t* __restrict__ k_lo,
    ushort_t* __restrict__ vT)
{
    // per buf (20480 ushorts = 40KB): Xh [0,4096) Xl [4096,8192)
    //                                 Wh [8192,14336) Wl [14336,20480)
    __shared__ ushort_t S[2][20480];   // 80 KB total

    const int tid = threadIdx.x;
    const int wv = tid >> 6, lane = tid & 63, g = lane >> 4, i = lane & 15;
    const int bb = (int)blockIdx.x;
    const int R0 = (bb >> 1) * 64, h = bb & 1;
    const int rh = wv >> 1, cq = wv & 1;
    const int sub = lane >> 3, s = lane & 7;
    const f32x4 zero4 = {0.f, 0.f, 0.f, 0.f};

    auto stage = [&](int buf, int t) {
        const int kb = t * 64;
#pragma unroll
        for (int j = 0; j < 10; ++j) {
            const int c = wv + 4 * j;
            ushort_t* dst = &S[buf][c << 9];
            const ushort_t* src;
            if (j < 4) {
                const int r = ((c & 7) << 3) + sub;            // 0..63
                src = (j < 2 ? x_hi : x_lo) +
                      (size_t)(R0 + r) * DM + kb + ((s ^ (r & 7)) << 3);
            } else if (j < 7) {
                const int wc = ((c - 16) << 3) + sub;          // 0..95
                src = wT_hi + (size_t)(h * 96 + wc) * DM + kb + ((s ^ (wc & 7)) << 3);
            } else {
                const int wc = ((c - 28) << 3) + sub;          // 0..95
                src = wT_lo + (size_t)(h * 96 + wc) * DM + kb + ((s ^ (wc & 7)) << 3);
            }
            gld_lds16(src, dst);
        }
    };

    f32x4 acc[2][3] = {{zero4, zero4, zero4}, {zero4, zero4, zero4}};

    stage(0, 0);   // prologue: 10 DMA issues/wave

    for (int t = 0; t < 16; ++t) {
        const int cur = t & 1;
        if (t + 1 < 16) {
            stage(cur ^ 1, t + 1);                            // next step in flight
            asm volatile("s_waitcnt vmcnt(10)" ::: "memory"); // own step-t DMAs done
        } else {
            asm volatile("s_waitcnt vmcnt(0)" ::: "memory");
        }
        __builtin_amdgcn_s_barrier();   // step t staged by all 4 waves

        const ushort_t* Sb = S[cur];
        short8 ah[2][2], al[2][2], bh[3][2], bl[3][2];
#pragma unroll
        for (int a = 0; a < 2; ++a) {
            const int r = (rh << 5) + (a << 4) + i;
#pragma unroll
            for (int kf = 0; kf < 2; ++kf) {
                const int off = (r << 6) + (((g + (kf << 2)) ^ (r & 7)) << 3);
                ah[a][kf] = *(const short8*)&Sb[off];
                al[a][kf] = *(const short8*)&Sb[4096 + off];
            }
        }
#pragma unroll
        for (int ct = 0; ct < 3; ++ct) {
            const int wc = cq * 48 + (ct << 4) + i;
#pragma unroll
            for (int kf = 0; kf < 2; ++kf) {
                const int off = (wc << 6) + (((g + (kf << 2)) ^ (wc & 7)) << 3);
                bh[ct][kf] = *(const short8*)&Sb[8192 + off];
                bl[ct][kf] = *(const short8*)&Sb[14336 + off];
            }
        }
#pragma unroll
        for (int a = 0; a < 2; ++a)
#pragma unroll
            for (int ct = 0; ct < 3; ++ct) {
                f32x4 v = acc[a][ct];
                v = MFMA16(ah[a][0], bh[ct][0], v);
                v = MFMA16(ah[a][1], bh[ct][1], v);
                v = MFMA16(ah[a][0], bl[ct][0], v);
                v = MFMA16(ah[a][1], bl[ct][1], v);
                v = MFMA16(al[a][0], bh[ct][0], v);
                v = MFMA16(al[a][1], bh[ct][1], v);
                acc[a][ct] = v;
            }
        // my LDS reads landed in regs -> safe for others to overwrite buf
        asm volatile("s_waitcnt lgkmcnt(0)" ::: "memory");
        __builtin_amdgcn_s_barrier();
    }

    // epilogue: wave tile = rows R0+rh*32 .. +31, ctids h*6+cq*3 .. +2
#pragma unroll
    for (int ct = 0; ct < 3; ++ct) {
        const int ctid = h * 6 + cq * 3 + ct;
        const int col = (ctid << 4) + i;
        const float bias = b[col];
#pragma unroll
        for (int a = 0; a < 2; ++a) {
            const int row0 = R0 + (rh << 5) + (a << 4) + (g << 2);
            if (ctid < 4) {        // q: pre-scale by log2e
#pragma unroll
                for (int reg = 0; reg < 4; ++reg) {
                    ushort_t hh, ll; split2((acc[a][ct][reg] + bias) * LOG2E, hh, ll);
                    q_hi[(row0 + reg) * KD + col] = hh;
                    q_lo[(row0 + reg) * KD + col] = ll;
                }
            } else if (ctid < 8) { // k
                const int c2 = col - 64;
#pragma unroll
                for (int reg = 0; reg < 4; ++reg) {
                    ushort_t hh, ll; split2(acc[a][ct][reg] + bias, hh, ll);
                    k_hi[(row0 + reg) * KD + c2] = hh;
                    k_lo[(row0 + reg) * KD + c2] = ll;
                }
            } else {               // v -> transposed bf16
                union { ushort_t u[4]; uint2 v; } pk;
#pragma unroll
                for (int reg = 0; reg < 4; ++reg) pk.u[reg] = rne(acc[a][ct][reg] + bias);
                *(uint2*)&vT[(size_t)(col - 128) * N_TOK + row0] = pk.v;
            }
        }
    }
}

// ---------------- Kernel 2: dense-grid LDS-pipelined causal flash attention ----------------
// Round-8 lesson: occupancy pins at ~8 waves/CU regardless of grid shape ->
// the wall is per-tile latency, not dispatch. This version (back to the 4-wave
// 64-row geometry that measured 59us) moves V through the SAME LDS-DMA
// pipeline as K: V's global fetch gets a full tile of vmcnt-counted lead
// (was: 8 global loads covered only by softmax), the 4 waves share one V copy
// (L2 traffic /4), and PV reads V via swizzled ds_read_b128 (~120cyc, free
// 2-way). Buffers: [2][Khi|Klo|V] = 48KB. 6 DMA/wave/tile, vmcnt(6).
// T5 setprio around both MFMA clusters. Dense causal-active enumeration +
// defer-max (T13) retained.
__global__ __launch_bounds__(256) void attn_kernel(
    const ushort_t* __restrict__ q_hi, const ushort_t* __restrict__ q_lo,
    const ushort_t* __restrict__ k_hi, const ushort_t* __restrict__ k_lo,
    const ushort_t* __restrict__ vT,
    float* __restrict__ Opart, float* __restrict__ MLpart,
    const int* __restrict__ causal_p, const int LC, const int ACT)
{
    __shared__ ushort_t Kls[2][3][4096];   // [buf][Khi/Klo/V][64x64], 48 KB

    const int tid = threadIdx.x;
    const int wv = tid >> 6, lane = tid & 63, g = lane >> 4, i = lane & 15;
    const int causal = *causal_p;
    const f32x4 zero4 = {0.f, 0.f, 0.f, 0.f};
    const int ibase = ((i >> 2) << 3) + (i & 3);

    const int bb = (int)blockIdx.x;
    int gb, chunk;
    if (bb < ACT) {
        // dense causal-active enumeration: gb = (a<<LC)+b2, chunks 0..a per
        // group row; cumulative C(a,b2) = a(a+1)*Q + b2*(a+1), Q = 1<<(LC-1).
        const int Q = 1 << (LC - 1);
        int a = (int)((sqrtf((float)bb / (float)Q + 0.25f) - 0.5f));
        while (a > 0 && a * (a + 1) * Q > bb) --a;
        while ((a + 1) * (a + 2) * Q <= bb) ++a;
        const int r = bb - a * (a + 1) * Q;
        const int b2 = r / (a + 1);
        chunk = r - b2 * (a + 1);
        gb = (a << LC) + b2;
    } else {
        const int j = bb - ACT;                 // complement pairs (above diag)
        gb = j & 127; chunk = j >> 7;
        if (chunk <= (gb >> LC)) return;        // covered by dense part
    }
    const int nkt = causal ? gb + 1 : (N_TOK / 64);
    const int t0 = chunk << LC;
    if (t0 >= nkt) return;                      // inactive (causal complement)
    const int tmax = t0 + (1 << LC);
    const int t1 = tmax < nkt ? tmax : nkt;
    const int R0w = (gb << 6) + (wv << 4);      // wave's q-row base

    const short8 qh0 = *(const short8*)&q_hi[(R0w + i) * KD + g * 8];
    const short8 qh1 = *(const short8*)&q_hi[(R0w + i) * KD + 32 + g * 8];
    const short8 ql0 = *(const short8*)&q_lo[(R0w + i) * KD + g * 8];
    const short8 ql1 = *(const short8*)&q_lo[(R0w + i) * KD + 32 + g * 8];

    // stage K hi/lo + V tile t into buffer nb: wave wv covers 1KB chunks
    // {wv, wv+4} of each 8KB matrix (6 DMA issues/wave). LDS write linear
    // (HW); global SOURCE slot pre-permuted (rule #21). For K, LDS row = key;
    // for V, LDS row = d. Same XOR swizzle (2 lanes/slot-group = free).
    const int srow = lane >> 3;      // row within chunk (0..7)
    const int sslot = lane & 7;      // 16B slot within row
    auto stageK = [&](int nb, int t) {
        const int kb2 = t << 6;
#pragma unroll
        for (int h = 0; h < 2; ++h) {
            const int ch = wv + (h << 2);
            const int row = (ch << 3) + srow;
            const int sw = ((row & 3) << 1) | ((row >> 3) & 1);
            const int slot = (sslot ^ sw) << 3;
            const size_t ksrc = (size_t)(kb2 + row) * KD + slot;
            gld_lds16(&k_hi[ksrc], &Kls[nb][0][ch << 9]);
            gld_lds16(&k_lo[ksrc], &Kls[nb][1][ch << 9]);
            gld_lds16(&vT[(size_t)row * N_TOK + kb2 + slot], &Kls[nb][2][ch << 9]);
        }
    };

    f32x4 o4[4] = {zero4, zero4, zero4, zero4};
    float runm = -1e30f, runl = 0.f;

    stageK(0, t0);   // prologue: 6 lds-DMA issues/wave

    for (int t = t0; t < t1; ++t) {
        const int cur = (t - t0) & 1;
        const int kb = t << 6;
        const bool more = (t + 1 < t1);

        if (more) {
            stageK(cur ^ 1, t + 1);                       // next tile in flight
            asm volatile("s_waitcnt vmcnt(6)" ::: "memory");   // own tile-t DMAs done
        } else {
            asm volatile("s_waitcnt vmcnt(0)" ::: "memory");
        }
        __builtin_amdgcn_s_barrier();   // tile t staged by all 4 waves

        f32x4 s4[4];
        __builtin_amdgcn_s_setprio(1);
#pragma unroll
        for (int ct = 0; ct < 4; ++ct) {
            const int r = ((ct & 1) << 2) + ((ct >> 1) << 5) + ibase;
            const int sw = ((r & 3) << 1) | ((r >> 3) & 1);
            const ushort_t* khp = &Kls[cur][0][r << 6];
            const ushort_t* klp = &Kls[cur][1][r << 6];
            const short8 kh0 = *(const short8*)&khp[(g ^ sw) << 3];
            const short8 kh1 = *(const short8*)&khp[((g + 4) ^ sw) << 3];
            const short8 kl0 = *(const short8*)&klp[(g ^ sw) << 3];
            const short8 kl1 = *(const short8*)&klp[((g + 4) ^ sw) << 3];
            f32x4 a = MFMA16(kh0, qh0, zero4);
            a = MFMA16(kh1, qh1, a);
            a = MFMA16(kh0, ql0, a);
            a = MFMA16(kh1, ql1, a);
            a = MFMA16(kl0, qh0, a);
            a = MFMA16(kl1, qh1, a);
            s4[ct] = a;
        }
        __builtin_amdgcn_s_setprio(0);

        if (causal && (kb + 64 > R0w)) {  // diagonal tile only
#pragma unroll
            for (int ct = 0; ct < 4; ++ct) {
                const int kba = kb + ((ct & 1) << 2) + ((ct >> 1) << 5);
#pragma unroll
                for (int reg = 0; reg < 4; ++reg) {
                    const int key = kba + (g << 3) + reg;
                    s4[ct][reg] = (key <= R0w + i) ? s4[ct][reg] : -1e30f;
                }
            }
        }
        // online softmax: lane owns qrow i; scalar state; defer-max THR=8
        float mx = -1e30f;
#pragma unroll
        for (int ct = 0; ct < 4; ++ct)
#pragma unroll
            for (int reg = 0; reg < 4; ++reg) mx = fmaxf(mx, s4[ct][reg]);
        mx = fmaxf(mx, __shfl_xor(mx, 16));
        mx = fmaxf(mx, __shfl_xor(mx, 32));
        const bool defer = __all(mx - runm <= 8.0f);
        const float nm = defer ? runm : fmaxf(runm, mx);
        const float al = defer ? 1.0f : ex2(runm - nm);
        runm = nm;
        float rs = 0.f;
#pragma unroll
        for (int ct = 0; ct < 4; ++ct)
#pragma unroll
            for (int reg = 0; reg < 4; ++reg) {
                const float p = ex2(s4[ct][reg] - nm);
                s4[ct][reg] = p;
                rs += p;
            }
        rs += __shfl_xor(rs, 16);
        rs += __shfl_xor(rs, 32);
        runl = runl * al + rs;
        if (!defer) {
#pragma unroll
            for (int ct2 = 0; ct2 < 4; ++ct2)
#pragma unroll
                for (int reg = 0; reg < 4; ++reg) o4[ct2][reg] *= al;
        }
        // P^T B-frags: pure register repack
        short8 pb0, pb1;
        {
            union { unsigned w[4]; short8 v; } u;
            u.w[0] = bfpack(s4[0][0], s4[0][1]); u.w[1] = bfpack(s4[0][2], s4[0][3]);
            u.w[2] = bfpack(s4[1][0], s4[1][1]); u.w[3] = bfpack(s4[1][2], s4[1][3]);
            pb0 = u.v;
            u.w[0] = bfpack(s4[2][0], s4[2][1]); u.w[1] = bfpack(s4[2][2], s4[2][3]);
            u.w[2] = bfpack(s4[3][0], s4[3][1]); u.w[3] = bfpack(s4[3][2], s4[3][3]);
            pb1 = u.v;
        }
        // PV: V fragments from LDS (same swizzle; row = d)
        const ushort_t* Vb = &Kls[cur][2][0];
        __builtin_amdgcn_s_setprio(1);
#pragma unroll
        for (int ct2 = 0; ct2 < 4; ++ct2) {
            const int r2 = ct2 * 16 + i;
            const int sw2 = ((r2 & 3) << 1) | ((r2 >> 3) & 1);
            const short8 va0 = *(const short8*)&Vb[(r2 << 6) + ((g ^ sw2) << 3)];
            const short8 va1 = *(const short8*)&Vb[(r2 << 6) + (((g + 4) ^ sw2) << 3)];
            o4[ct2] = MFMA16(va0, pb0, o4[ct2]);
            o4[ct2] = MFMA16(va1, pb1, o4[ct2]);
        }
        __builtin_amdgcn_s_setprio(0);
        // all my LDS reads (K and V) landed -> safe for others to overwrite buf
        asm volatile("s_waitcnt lgkmcnt(0)" ::: "memory");
        __builtin_amdgcn_s_barrier();
    }

    // epilogue: each wave owns the full (qt = gb*4+wv, chunk) partial
    const int pidx = ((gb << (7 - LC)) + chunk) * 4 + wv;
#pragma unroll
    for (int ct2 = 0; ct2 < 4; ++ct2)
#pragma unroll
        for (int reg = 0; reg < 4; ++reg) {
            const int d = ct2 * 16 + 4 * g + reg;
            Opart[((size_t)pidx * 16 + i) * 64 + d] = o4[ct2][reg];
        }
    if (lane < 16) {
        MLpart[pidx * 32 + lane] = runm;
        MLpart[pidx * 32 + 16 + lane] = runl;
    }
}

// ---------------- Kernel 3a: split-K merge (massively parallel) ----------------
// One thread per (row, d) = 524288 threads = 2048 blocks, zero LDS ->
// ~32 waves/CU; pure TLP hides the load latency, Opart read exactly once.
// Writes normalized bf16 hi/lo ao[8192][64] into the dead q_hi/q_lo region.
__global__ __launch_bounds__(256) void merge_kernel(
    const float* __restrict__ Opart, const float* __restrict__ MLpart,
    ushort_t* __restrict__ aoh, ushort_t* __restrict__ aol,
    const int* __restrict__ causal_p, const int LC)
{
    const int idx = blockIdx.x * 256 + threadIdx.x;
    const int d = idx & 63, row = idx >> 6;               // row 0..8191
    const int r = row & 15, qtile = row >> 4, gb = row >> 6;
    const int causal = *causal_p;
    const int nkt = causal ? gb + 1 : (N_TOK / 64);
    const int nch = (nkt + (1 << LC) - 1) >> LC;          // 1..16
    const int pb = ((gb << (7 - LC)) << 2) + (qtile & 3); // pidx(c) = pb + 4c
    float m[16], l[16];
#pragma unroll
    for (int c = 0; c < 16; ++c) {
        if (c < nch) {
            m[c] = MLpart[(pb + 4 * c) * 32 + r];
            l[c] = MLpart[(pb + 4 * c) * 32 + 16 + r];
        } else { m[c] = -1e30f; l[c] = 0.f; }
    }
    float M = m[0];
#pragma unroll
    for (int c = 1; c < 16; ++c) M = fmaxf(M, m[c]);
    float den = 0.f, O = 0.f;
#pragma unroll
    for (int c = 0; c < 16; ++c) {
        const float e = ex2(m[c] - M);
        den += l[c] * e;
        if (c < nch)
            O += Opart[((size_t)(pb + 4 * c) * 16 + r) * 64 + d] * e;
    }
    ushort_t h, lo2; split2(O / den, h, lo2);
    aoh[row * 64 + d] = h;
    aol[row * 64 + d] = lo2;
}

// ---------------- Kernel 3b: output projection (pure GEMM) ----------------
// grid 2048 x 256. Block (qtile=b>>2, qa=b&3): A-frags direct from global ao
// (2MB, L2-resident, 4x reuse), no LDS/sync; MFMA project col quarter qa.
__global__ __launch_bounds__(256) void proj_kernel(
    const ushort_t* __restrict__ aoh, const ushort_t* __restrict__ aol,
    const ushort_t* __restrict__ woT_hi, const ushort_t* __restrict__ woT_lo,
    const float* __restrict__ bo, float* __restrict__ out)
{
    const int tid = threadIdx.x;
    const int wv = tid >> 6, lane = tid & 63, g = lane >> 4, i = lane & 15;
    const int bb = (int)blockIdx.x;
    const int qtile = bb >> 2, qa = bb & 3;
    const int R0 = qtile << 4;
    const f32x4 zero4 = {0.f, 0.f, 0.f, 0.f};
    const short8 ah0 = *(const short8*)&aoh[(R0 + i) * 64 + g * 8];
    const short8 ah1 = *(const short8*)&aoh[(R0 + i) * 64 + 32 + g * 8];
    const short8 al0 = *(const short8*)&aol[(R0 + i) * 64 + g * 8];
    const short8 al1 = *(const short8*)&aol[(R0 + i) * 64 + 32 + g * 8];
#pragma unroll
    for (int cc = 0; cc < 4; ++cc) {
        const int col = (qa << 8) + ((wv << 2) + cc) * 16 + i;
        const short8 bh0 = *(const short8*)&woT_hi[col * KD + g * 8];
        const short8 bh1 = *(const short8*)&woT_hi[col * KD + 32 + g * 8];
        const short8 bl0 = *(const short8*)&woT_lo[col * KD + g * 8];
        const short8 bl1 = *(const short8*)&woT_lo[col * KD + 32 + g * 8];
        f32x4 acc = MFMA16(ah0, bh0, zero4);
        acc = MFMA16(ah1, bh1, acc);
        acc = MFMA16(ah0, bl0, acc);
        acc = MFMA16(ah1, bl1, acc);
        acc = MFMA16(al0, bh0, acc);
        acc = MFMA16(al1, bh1, acc);
        const float bias = bo[col];
#pragma unroll
        for (int reg = 0; reg < 4; ++reg)
            out[(size_t)(R0 + 4 * g + reg) * ODIM + col] = acc[reg] + bias;
    }
}

extern "C" void kernel_launch(void* const* d_in, const int* in_sizes, int n_in,
                              void* d_out, int out_size, void* d_ws, size_t ws_size,
                              hipStream_t stream) {
    const float* x     = (const float*)d_in[0];
    const float* w_qkv = (const float*)d_in[1];
    const float* b_qkv = (const float*)d_in[2];
    const float* w_out = (const float*)d_in[3];
    const float* b_out = (const float*)d_in[4];
    const int* causal  = (const int*)d_in[5];
    float* out         = (float*)d_out;

    // Chunk size: 8 K-tiles (LC=3) needs 39 MB workspace; fall back to 16
    // (LC=4, 23 MB) if the workspace is tight.
    const int LC  = (ws_size >= ((size_t)39 << 20)) ? 3 : 4;
    const int NCH = 128 >> LC;                 // max chunks per gb
    const int NA  = 128 >> LC;                 // dense a-groups
    const int ACT = (1 << LC) * NA * (NA + 1) / 2;   // causal-active blocks (1088/576)
    const size_t opart_bytes = (size_t)128 * NCH * 4 * 16 * 64 * 4;  // 32 or 16 MB

    char* ws = (char*)d_ws;
    ushort_t* wT_hi  = (ushort_t*)(ws);                    // 384 KB
    ushort_t* wT_lo  = (ushort_t*)(ws + 393216);           // 384 KB
    ushort_t* woT_hi = (ushort_t*)(ws + 786432);           // 128 KB
    ushort_t* woT_lo = (ushort_t*)(ws + 917504);           // 128 KB -> 1 MB
    ushort_t* q_hi   = (ushort_t*)(ws + (1u << 20));
    ushort_t* q_lo   = (ushort_t*)(ws + (2u << 20));
    ushort_t* k_hi   = (ushort_t*)(ws + (3u << 20));
    ushort_t* k_lo   = (ushort_t*)(ws + (4u << 20));
    ushort_t* vT     = (ushort_t*)(ws + (5u << 20));       // -> 6 MB
    // x_hi/x_lo [6MB..38MB) are consumed by qkv BEFORE attn writes
    // Opart/MLpart (same region) -> temporal overlap is safe (in-order stream).
    ushort_t* x_hi   = (ushort_t*)(ws + (6u << 20));       // 16 MB
    ushort_t* x_lo   = (ushort_t*)(ws + (22u << 20));      // 16 MB -> 38 MB
    float*    Opart  = (float*)(ws + (6u << 20));          // 32/16 MB (after qkv)
    float*    MLpart = (float*)(ws + (6u << 20) + opart_bytes);  // 1/0.5 MB
    // ao (merged, normalized bf16 hi/lo, 1 MB each) overlays the dead q_hi /
    // q_lo regions (q consumed by attn; in-order stream -> safe).
    ushort_t* aoh    = (ushort_t*)(ws + (1u << 20));
    ushort_t* aol    = (ushort_t*)(ws + (2u << 20));

    prep_kernel<<<5120, 256, 0, stream>>>(w_qkv, w_out, x, wT_hi, wT_lo,
                                          woT_hi, woT_lo, x_hi, x_lo);
    qkv_kernel<<<256, 256, 0, stream>>>(x_hi, x_lo, wT_hi, wT_lo, b_qkv,
                                        q_hi, q_lo, k_hi, k_lo, vT);
    attn_kernel<<<ACT + NCH * 128, 256, 0, stream>>>(q_hi, q_lo, k_hi, k_lo, vT,
                                                     Opart, MLpart, causal, LC, ACT);
    merge_kernel<<<2048, 256, 0, stream>>>(Opart, MLpart, aoh, aol, causal, LC);
    proj_kernel<<<2048, 256, 0, stream>>>(aoh, aol, woT_hi, woT_lo, b_out, out);
}

// Round 10
// 167.925 us; speedup vs baseline: 1.1881x; 1.0392x over previous
//
#include <hip/hip_runtime.h>
#include <hip/hip_bf16.h>
#include <math.h>

#define N_TOK 8192
#define DM 1024
#define KD 64
#define ODIM 1024
#define LOG2E 1.4426950408889634f
#define CH 12            // attn chunk size in K-tiles (748 active blocks = 2.92/CU < 3-cap)
#define NCHNK 11         // ceil(128/CH)
#define ACTB 748         // sum_{a=0}^{9} 12(a+1) + 8*11

typedef unsigned short ushort_t;
typedef __attribute__((ext_vector_type(8))) short short8;
typedef __attribute__((ext_vector_type(4))) float f32x4;

#define MFMA16(a, b, c) __builtin_amdgcn_mfma_f32_16x16x32_bf16((a), (b), (c), 0, 0, 0)

__device__ __forceinline__ float ex2(float x) {
#if __has_builtin(__builtin_amdgcn_exp2f)
    return __builtin_amdgcn_exp2f(x);
#else
    return exp2f(x);
#endif
}
// RNE float->bf16 (finite inputs)
__device__ __forceinline__ ushort_t rne(float x) {
    unsigned u = __float_as_uint(x);
    u += 0x7fffu + ((u >> 16) & 1u);
    return (ushort_t)(u >> 16);
}
__device__ __forceinline__ float ubf(ushort_t h) {
    return __uint_as_float(((unsigned)h) << 16);
}
__device__ __forceinline__ void split2(float x, ushort_t& hi, ushort_t& lo) {
    hi = rne(x);
    lo = rne(x - ubf(hi));
}
// packed f32x2 -> bf16x2 (RNE), lo = a, hi = b: 1 VALU inst vs ~6 for manual
__device__ __forceinline__ unsigned cvtpk(float a, float b) {
    unsigned r;
    asm("v_cvt_pk_bf16_f32 %0, %1, %2" : "=v"(r) : "v"(a), "v"(b));
    return r;
}
// async global->LDS, 16B per lane; lds dst must be wave-uniform base (+lane*16 implicit)
__device__ __forceinline__ void gld_lds16(const void* g, void* l) {
    __builtin_amdgcn_global_load_lds(
        (const __attribute__((address_space(1))) unsigned int*)g,
        (__attribute__((address_space(3))) unsigned int*)l, 16, 0, 0);
}

// ---------------- Kernel 0: weight transpose + x hi/lo pre-split ----------------
// grid 5120 x 256. idx<192K: w_qkv transpose+split; <256K: w_out; rest: x
// pre-split (8 elems/thread) so qkv's inner loop has NO VALU conversion chain.
__global__ __launch_bounds__(256) void prep_kernel(
    const float* __restrict__ wq, const float* __restrict__ wo,
    const float* __restrict__ x,
    ushort_t* __restrict__ wT_hi, ushort_t* __restrict__ wT_lo,
    ushort_t* __restrict__ woT_hi, ushort_t* __restrict__ woT_lo,
    ushort_t* __restrict__ x_hi, ushort_t* __restrict__ x_lo)
{
    const int idx = blockIdx.x * 256 + threadIdx.x;
    if (idx < 192 * 1024) {
        const int c = idx >> 10, k = idx & 1023;
        ushort_t h, l; split2(wq[k * 192 + c], h, l);
        wT_hi[idx] = h; wT_lo[idx] = l;
    } else if (idx < 256 * 1024) {
        const int j = idx - 192 * 1024;
        const int c = j >> 6, k = j & 63;
        ushort_t h, l; split2(wo[k * ODIM + c], h, l);
        woT_hi[j] = h; woT_lo[j] = l;
    } else {
        const size_t j = (size_t)(idx - 256 * 1024) * 8;   // 1M threads x 8 elems
        const float4 xa = *(const float4*)&x[j];
        const float4 xb = *(const float4*)&x[j + 4];
        const float xe[8] = {xa.x, xa.y, xa.z, xa.w, xb.x, xb.y, xb.z, xb.w};
        union { short8 v; ushort_t u[8]; } hh, ll;
#pragma unroll
        for (int e = 0; e < 8; ++e) { split2(xe[e], hh.u[e], ll.u[e]); }
        *(short8*)&x_hi[j] = hh.v;
        *(short8*)&x_lo[j] = ll.v;
    }
}

// ---------------- Kernel 1: LDS-pipelined QKV projection GEMM ----------------
// grid 256 x 256. Block = 64 rows (R0 = (bb>>1)*64) x 96-col half (h = bb&1);
// 4 waves in 2x2 grid, wave tile 32 rows x 48 cols. Round-4 lesson: register
// pipelines get un-rolled by the compiler -> use the DMA schedule the compiler
// CANNOT undo: global_load_lds, counted vmcnt asm, double-buffered LDS.
__global__ __launch_bounds__(256) void qkv_kernel(
    const ushort_t* __restrict__ x_hi, const ushort_t* __restrict__ x_lo,
    const ushort_t* __restrict__ wT_hi, const ushort_t* __restrict__ wT_lo,
    const float* __restrict__ b,
    ushort_t* __restrict__ q_hi, ushort_t* __restrict__ q_lo,
    ushort_t* __restrict__ k_hi, ushort_t* __restrict__ k_lo,
    ushort_t* __restrict__ vT)
{
    // per buf (20480 ushorts = 40KB): Xh [0,4096) Xl [4096,8192)
    //                                 Wh [8192,14336) Wl [14336,20480)
    __shared__ ushort_t S[2][20480];   // 80 KB total

    const int tid = threadIdx.x;
    const int wv = tid >> 6, lane = tid & 63, g = lane >> 4, i = lane & 15;
    const int bb = (int)blockIdx.x;
    const int R0 = (bb >> 1) * 64, h = bb & 1;
    const int rh = wv >> 1, cq = wv & 1;
    const int sub = lane >> 3, s = lane & 7;
    const f32x4 zero4 = {0.f, 0.f, 0.f, 0.f};

    auto stage = [&](int buf, int t) {
        const int kb = t * 64;
#pragma unroll
        for (int j = 0; j < 10; ++j) {
            const int c = wv + 4 * j;
            ushort_t* dst = &S[buf][c << 9];
            const ushort_t* src;
            if (j < 4) {
                const int r = ((c & 7) << 3) + sub;            // 0..63
                src = (j < 2 ? x_hi : x_lo) +
                      (size_t)(R0 + r) * DM + kb + ((s ^ (r & 7)) << 3);
            } else if (j < 7) {
                const int wc = ((c - 16) << 3) + sub;          // 0..95
                src = wT_hi + (size_t)(h * 96 + wc) * DM + kb + ((s ^ (wc & 7)) << 3);
            } else {
                const int wc = ((c - 28) << 3) + sub;          // 0..95
                src = wT_lo + (size_t)(h * 96 + wc) * DM + kb + ((s ^ (wc & 7)) << 3);
            }
            gld_lds16(src, dst);
        }
    };

    f32x4 acc[2][3] = {{zero4, zero4, zero4}, {zero4, zero4, zero4}};

    stage(0, 0);   // prologue: 10 DMA issues/wave

    for (int t = 0; t < 16; ++t) {
        const int cur = t & 1;
        if (t + 1 < 16) {
            stage(cur ^ 1, t + 1);                            // next step in flight
            asm volatile("s_waitcnt vmcnt(10)" ::: "memory"); // own step-t DMAs done
        } else {
            asm volatile("s_waitcnt vmcnt(0)" ::: "memory");
        }
        __builtin_amdgcn_s_barrier();   // step t staged by all 4 waves

        const ushort_t* Sb = S[cur];
        short8 ah[2][2], al[2][2], bh[3][2], bl[3][2];
#pragma unroll
        for (int a = 0; a < 2; ++a) {
            const int r = (rh << 5) + (a << 4) + i;
#pragma unroll
            for (int kf = 0; kf < 2; ++kf) {
                const int off = (r << 6) + (((g + (kf << 2)) ^ (r & 7)) << 3);
                ah[a][kf] = *(const short8*)&Sb[off];
                al[a][kf] = *(const short8*)&Sb[4096 + off];
            }
        }
#pragma unroll
        for (int ct = 0; ct < 3; ++ct) {
            const int wc = cq * 48 + (ct << 4) + i;
#pragma unroll
            for (int kf = 0; kf < 2; ++kf) {
                const int off = (wc << 6) + (((g + (kf << 2)) ^ (wc & 7)) << 3);
                bh[ct][kf] = *(const short8*)&Sb[8192 + off];
                bl[ct][kf] = *(const short8*)&Sb[14336 + off];
            }
        }
#pragma unroll
        for (int a = 0; a < 2; ++a)
#pragma unroll
            for (int ct = 0; ct < 3; ++ct) {
                f32x4 v = acc[a][ct];
                v = MFMA16(ah[a][0], bh[ct][0], v);
                v = MFMA16(ah[a][1], bh[ct][1], v);
                v = MFMA16(ah[a][0], bl[ct][0], v);
                v = MFMA16(ah[a][1], bl[ct][1], v);
                v = MFMA16(al[a][0], bh[ct][0], v);
                v = MFMA16(al[a][1], bh[ct][1], v);
                acc[a][ct] = v;
            }
        // my LDS reads landed in regs -> safe for others to overwrite buf
        asm volatile("s_waitcnt lgkmcnt(0)" ::: "memory");
        __builtin_amdgcn_s_barrier();
    }

    // epilogue: wave tile = rows R0+rh*32 .. +31, ctids h*6+cq*3 .. +2
#pragma unroll
    for (int ct = 0; ct < 3; ++ct) {
        const int ctid = h * 6 + cq * 3 + ct;
        const int col = (ctid << 4) + i;
        const float bias = b[col];
#pragma unroll
        for (int a = 0; a < 2; ++a) {
            const int row0 = R0 + (rh << 5) + (a << 4) + (g << 2);
            if (ctid < 4) {        // q: pre-scale by log2e
#pragma unroll
                for (int reg = 0; reg < 4; ++reg) {
                    ushort_t hh, ll; split2((acc[a][ct][reg] + bias) * LOG2E, hh, ll);
                    q_hi[(row0 + reg) * KD + col] = hh;
                    q_lo[(row0 + reg) * KD + col] = ll;
                }
            } else if (ctid < 8) { // k
                const int c2 = col - 64;
#pragma unroll
                for (int reg = 0; reg < 4; ++reg) {
                    ushort_t hh, ll; split2(acc[a][ct][reg] + bias, hh, ll);
                    k_hi[(row0 + reg) * KD + c2] = hh;
                    k_lo[(row0 + reg) * KD + c2] = ll;
                }
            } else {               // v -> transposed bf16
                union { ushort_t u[4]; uint2 v; } pk;
#pragma unroll
                for (int reg = 0; reg < 4; ++reg) pk.u[reg] = rne(acc[a][ct][reg] + bias);
                *(uint2*)&vT[(size_t)(col - 128) * N_TOK + row0] = pk.v;
            }
        }
    }
}

// ---------------- Kernel 2: CH=12-chunked LDS-pipelined causal flash attention ----------------
// Round-9 lesson: LDS 48KB caps 3 blocks/CU but 1088 active blocks = 4.25/CU
// -> a second serial generation (occupancy 18.3% vs 37.5% cap). Fix: chunk
// size CH=12 K-tiles -> ACT = sum_gb ceil((gb+1)/12) = 748 = 2.92/CU: ALL
// active blocks co-resident, single generation. Dense enumeration: group
// a = gb/12 has a+1 chunks per gb; CUM(a) = 6a(a+1); invert with sqrt+fixup
// (partial group a=10 at bb>=660 handled exactly). Complement 128x11 appended
// (instant-exit when causal; real work when non-causal).
// Inner loop identical to round 9 (K hi/lo + V through LDS DMA, vmcnt 6/0,
// XOR swizzle, setprio, defer-max) except the P-repack now uses
// v_cvt_pk_bf16_f32 (8 insts vs ~48 manual ones; VALU was the busiest pipe).
__global__ __launch_bounds__(256) void attn_kernel(
    const ushort_t* __restrict__ q_hi, const ushort_t* __restrict__ q_lo,
    const ushort_t* __restrict__ k_hi, const ushort_t* __restrict__ k_lo,
    const ushort_t* __restrict__ vT,
    float* __restrict__ Opart, float* __restrict__ MLpart,
    const int* __restrict__ causal_p)
{
    __shared__ ushort_t Kls[2][3][4096];   // [buf][Khi/Klo/V][64x64], 48 KB

    const int tid = threadIdx.x;
    const int wv = tid >> 6, lane = tid & 63, g = lane >> 4, i = lane & 15;
    const int causal = *causal_p;
    const f32x4 zero4 = {0.f, 0.f, 0.f, 0.f};
    const int ibase = ((i >> 2) << 3) + (i & 3);

    const int bb = (int)blockIdx.x;
    int gb, chunk;
    if (bb < ACTB) {
        if (bb >= 660) {                        // partial group a = 10
            const int r = bb - 660;
            const int b2 = r / 11;
            chunk = r - b2 * 11;
            gb = 120 + b2;
        } else {                                // full groups a = 0..9
            int a = (int)(sqrtf((float)bb / 6.0f + 0.25f) - 0.5f);
            while (a > 0 && 6 * a * (a + 1) > bb) --a;
            while (6 * (a + 1) * (a + 2) <= bb) ++a;
            const int r = bb - 6 * a * (a + 1);
            const int b2 = r / (a + 1);
            chunk = r - b2 * (a + 1);
            gb = 12 * a + b2;
        }
    } else {
        const int j = bb - ACTB;                // complement pairs
        gb = j & 127; chunk = j >> 7;           // chunk 0..10
        if (chunk <= gb / 12) return;           // covered by dense part
    }
    const int nkt = causal ? gb + 1 : (N_TOK / 64);
    const int t0 = chunk * CH;
    if (t0 >= nkt) return;                      // inactive (causal complement)
    const int tmax = t0 + CH;
    const int t1 = tmax < nkt ? tmax : nkt;
    const int R0w = (gb << 6) + (wv << 4);      // wave's q-row base

    const short8 qh0 = *(const short8*)&q_hi[(R0w + i) * KD + g * 8];
    const short8 qh1 = *(const short8*)&q_hi[(R0w + i) * KD + 32 + g * 8];
    const short8 ql0 = *(const short8*)&q_lo[(R0w + i) * KD + g * 8];
    const short8 ql1 = *(const short8*)&q_lo[(R0w + i) * KD + 32 + g * 8];

    // stage K hi/lo + V tile t into buffer nb: wave wv covers 1KB chunks
    // {wv, wv+4} of each 8KB matrix (6 DMA issues/wave). LDS write linear
    // (HW); global SOURCE slot pre-permuted (rule #21). For K, LDS row = key;
    // for V, LDS row = d. Same XOR swizzle (2 lanes/slot-group = free).
    const int srow = lane >> 3;      // row within chunk (0..7)
    const int sslot = lane & 7;      // 16B slot within row
    auto stageK = [&](int nb, int t) {
        const int kb2 = t << 6;
#pragma unroll
        for (int h = 0; h < 2; ++h) {
            const int ch = wv + (h << 2);
            const int row = (ch << 3) + srow;
            const int sw = ((row & 3) << 1) | ((row >> 3) & 1);
            const int slot = (sslot ^ sw) << 3;
            const size_t ksrc = (size_t)(kb2 + row) * KD + slot;
            gld_lds16(&k_hi[ksrc], &Kls[nb][0][ch << 9]);
            gld_lds16(&k_lo[ksrc], &Kls[nb][1][ch << 9]);
            gld_lds16(&vT[(size_t)row * N_TOK + kb2 + slot], &Kls[nb][2][ch << 9]);
        }
    };

    f32x4 o4[4] = {zero4, zero4, zero4, zero4};
    float runm = -1e30f, runl = 0.f;

    stageK(0, t0);   // prologue: 6 lds-DMA issues/wave

    for (int t = t0; t < t1; ++t) {
        const int cur = (t - t0) & 1;
        const int kb = t << 6;
        const bool more = (t + 1 < t1);

        if (more) {
            stageK(cur ^ 1, t + 1);                       // next tile in flight
            asm volatile("s_waitcnt vmcnt(6)" ::: "memory");   // own tile-t DMAs done
        } else {
            asm volatile("s_waitcnt vmcnt(0)" ::: "memory");
        }
        __builtin_amdgcn_s_barrier();   // tile t staged by all 4 waves

        f32x4 s4[4];
        __builtin_amdgcn_s_setprio(1);
#pragma unroll
        for (int ct = 0; ct < 4; ++ct) {
            const int r = ((ct & 1) << 2) + ((ct >> 1) << 5) + ibase;
            const int sw = ((r & 3) << 1) | ((r >> 3) & 1);
            const ushort_t* khp = &Kls[cur][0][r << 6];
            const ushort_t* klp = &Kls[cur][1][r << 6];
            const short8 kh0 = *(const short8*)&khp[(g ^ sw) << 3];
            const short8 kh1 = *(const short8*)&khp[((g + 4) ^ sw) << 3];
            const short8 kl0 = *(const short8*)&klp[(g ^ sw) << 3];
            const short8 kl1 = *(const short8*)&klp[((g + 4) ^ sw) << 3];
            f32x4 a = MFMA16(kh0, qh0, zero4);
            a = MFMA16(kh1, qh1, a);
            a = MFMA16(kh0, ql0, a);
            a = MFMA16(kh1, ql1, a);
            a = MFMA16(kl0, qh0, a);
            a = MFMA16(kl1, qh1, a);
            s4[ct] = a;
        }
        __builtin_amdgcn_s_setprio(0);

        if (causal && (kb + 64 > R0w)) {  // diagonal tile only
#pragma unroll
            for (int ct = 0; ct < 4; ++ct) {
                const int kba = kb + ((ct & 1) << 2) + ((ct >> 1) << 5);
#pragma unroll
                for (int reg = 0; reg < 4; ++reg) {
                    const int key = kba + (g << 3) + reg;
                    s4[ct][reg] = (key <= R0w + i) ? s4[ct][reg] : -1e30f;
                }
            }
        }
        // online softmax: lane owns qrow i; scalar state; defer-max THR=8
        float mx = -1e30f;
#pragma unroll
        for (int ct = 0; ct < 4; ++ct)
#pragma unroll
            for (int reg = 0; reg < 4; ++reg) mx = fmaxf(mx, s4[ct][reg]);
        mx = fmaxf(mx, __shfl_xor(mx, 16));
        mx = fmaxf(mx, __shfl_xor(mx, 32));
        const bool defer = __all(mx - runm <= 8.0f);
        const float nm = defer ? runm : fmaxf(runm, mx);
        const float al = defer ? 1.0f : ex2(runm - nm);
        runm = nm;
        float rs = 0.f;
#pragma unroll
        for (int ct = 0; ct < 4; ++ct)
#pragma unroll
            for (int reg = 0; reg < 4; ++reg) {
                const float p = ex2(s4[ct][reg] - nm);
                s4[ct][reg] = p;
                rs += p;
            }
        rs += __shfl_xor(rs, 16);
        rs += __shfl_xor(rs, 32);
        runl = runl * al + rs;
        if (!defer) {
#pragma unroll
            for (int ct2 = 0; ct2 < 4; ++ct2)
#pragma unroll
                for (int reg = 0; reg < 4; ++reg) o4[ct2][reg] *= al;
        }
        // P^T B-frags: packed cvt (1 inst per f32-pair)
        short8 pb0, pb1;
        {
            union { unsigned w[4]; short8 v; } u;
            u.w[0] = cvtpk(s4[0][0], s4[0][1]); u.w[1] = cvtpk(s4[0][2], s4[0][3]);
            u.w[2] = cvtpk(s4[1][0], s4[1][1]); u.w[3] = cvtpk(s4[1][2], s4[1][3]);
            pb0 = u.v;
            u.w[0] = cvtpk(s4[2][0], s4[2][1]); u.w[1] = cvtpk(s4[2][2], s4[2][3]);
            u.w[2] = cvtpk(s4[3][0], s4[3][1]); u.w[3] = cvtpk(s4[3][2], s4[3][3]);
            pb1 = u.v;
        }
        // PV: V fragments from LDS (same swizzle; row = d)
        const ushort_t* Vb = &Kls[cur][2][0];
        __builtin_amdgcn_s_setprio(1);
#pragma unroll
        for (int ct2 = 0; ct2 < 4; ++ct2) {
            const int r2 = ct2 * 16 + i;
            const int sw2 = ((r2 & 3) << 1) | ((r2 >> 3) & 1);
            const short8 va0 = *(const short8*)&Vb[(r2 << 6) + ((g ^ sw2) << 3)];
            const short8 va1 = *(const short8*)&Vb[(r2 << 6) + (((g + 4) ^ sw2) << 3)];
            o4[ct2] = MFMA16(va0, pb0, o4[ct2]);
            o4[ct2] = MFMA16(va1, pb1, o4[ct2]);
        }
        __builtin_amdgcn_s_setprio(0);
        // all my LDS reads (K and V) landed -> safe for others to overwrite buf
        asm volatile("s_waitcnt lgkmcnt(0)" ::: "memory");
        __builtin_amdgcn_s_barrier();
    }

    // epilogue: each wave owns the full (qt = gb*4+wv, chunk) partial
    const int pidx = (gb * NCHNK + chunk) * 4 + wv;
#pragma unroll
    for (int ct2 = 0; ct2 < 4; ++ct2)
#pragma unroll
        for (int reg = 0; reg < 4; ++reg) {
            const int d = ct2 * 16 + 4 * g + reg;
            Opart[((size_t)pidx * 16 + i) * 64 + d] = o4[ct2][reg];
        }
    if (lane < 16) {
        MLpart[pidx * 32 + lane] = runm;
        MLpart[pidx * 32 + 16 + lane] = runl;
    }
}

// ---------------- Kernel 3a: split-K merge (massively parallel) ----------------
// One thread per (row, d) = 524288 threads = 2048 blocks, zero LDS ->
// ~32 waves/CU; pure TLP hides the load latency, Opart read exactly once.
// Writes normalized bf16 hi/lo ao[8192][64] into the dead q_hi/q_lo region.
__global__ __launch_bounds__(256) void merge_kernel(
    const float* __restrict__ Opart, const float* __restrict__ MLpart,
    ushort_t* __restrict__ aoh, ushort_t* __restrict__ aol,
    const int* __restrict__ causal_p)
{
    const int idx = blockIdx.x * 256 + threadIdx.x;
    const int d = idx & 63, row = idx >> 6;               // row 0..8191
    const int r = row & 15, qtile = row >> 4, gb = row >> 6;
    const int causal = *causal_p;
    const int nkt = causal ? gb + 1 : (N_TOK / 64);
    const int nch = (nkt + CH - 1) / CH;                  // 1..11
    const int pb = (gb * NCHNK) * 4 + (qtile & 3);        // pidx(c) = pb + 4c
    float m[NCHNK], l[NCHNK];
#pragma unroll
    for (int c = 0; c < NCHNK; ++c) {
        if (c < nch) {
            m[c] = MLpart[(pb + 4 * c) * 32 + r];
            l[c] = MLpart[(pb + 4 * c) * 32 + 16 + r];
        } else { m[c] = -1e30f; l[c] = 0.f; }
    }
    float M = m[0];
#pragma unroll
    for (int c = 1; c < NCHNK; ++c) M = fmaxf(M, m[c]);
    float den = 0.f, O = 0.f;
#pragma unroll
    for (int c = 0; c < NCHNK; ++c) {
        const float e = ex2(m[c] - M);
        den += l[c] * e;
        if (c < nch)
            O += Opart[((size_t)(pb + 4 * c) * 16 + r) * 64 + d] * e;
    }
    ushort_t h, lo2; split2(O / den, h, lo2);
    aoh[row * 64 + d] = h;
    aol[row * 64 + d] = lo2;
}

// ---------------- Kernel 3b: output projection (pure GEMM) ----------------
// grid 2048 x 256. Block (qtile=b>>2, qa=b&3): A-frags direct from global ao
// (2MB, L2-resident, 4x reuse), no LDS/sync; MFMA project col quarter qa.
__global__ __launch_bounds__(256) void proj_kernel(
    const ushort_t* __restrict__ aoh, const ushort_t* __restrict__ aol,
    const ushort_t* __restrict__ woT_hi, const ushort_t* __restrict__ woT_lo,
    const float* __restrict__ bo, float* __restrict__ out)
{
    const int tid = threadIdx.x;
    const int wv = tid >> 6, lane = tid & 63, g = lane >> 4, i = lane & 15;
    const int bb = (int)blockIdx.x;
    const int qtile = bb >> 2, qa = bb & 3;
    const int R0 = qtile << 4;
    const f32x4 zero4 = {0.f, 0.f, 0.f, 0.f};
    const short8 ah0 = *(const short8*)&aoh[(R0 + i) * 64 + g * 8];
    const short8 ah1 = *(const short8*)&aoh[(R0 + i) * 64 + 32 + g * 8];
    const short8 al0 = *(const short8*)&aol[(R0 + i) * 64 + g * 8];
    const short8 al1 = *(const short8*)&aol[(R0 + i) * 64 + 32 + g * 8];
#pragma unroll
    for (int cc = 0; cc < 4; ++cc) {
        const int col = (qa << 8) + ((wv << 2) + cc) * 16 + i;
        const short8 bh0 = *(const short8*)&woT_hi[col * KD + g * 8];
        const short8 bh1 = *(const short8*)&woT_hi[col * KD + 32 + g * 8];
        const short8 bl0 = *(const short8*)&woT_lo[col * KD + g * 8];
        const short8 bl1 = *(const short8*)&woT_lo[col * KD + 32 + g * 8];
        f32x4 acc = MFMA16(ah0, bh0, zero4);
        acc = MFMA16(ah1, bh1, acc);
        acc = MFMA16(ah0, bl0, acc);
        acc = MFMA16(ah1, bl1, acc);
        acc = MFMA16(al0, bh0, acc);
        acc = MFMA16(al1, bh1, acc);
        const float bias = bo[col];
#pragma unroll
        for (int reg = 0; reg < 4; ++reg)
            out[(size_t)(R0 + 4 * g + reg) * ODIM + col] = acc[reg] + bias;
    }
}

extern "C" void kernel_launch(void* const* d_in, const int* in_sizes, int n_in,
                              void* d_out, int out_size, void* d_ws, size_t ws_size,
                              hipStream_t stream) {
    const float* x     = (const float*)d_in[0];
    const float* w_qkv = (const float*)d_in[1];
    const float* b_qkv = (const float*)d_in[2];
    const float* w_out = (const float*)d_in[3];
    const float* b_out = (const float*)d_in[4];
    const int* causal  = (const int*)d_in[5];
    float* out         = (float*)d_out;

    // Opart: 128 gb x 11 chunks x 4 qtiles = 5632 pidx x 4KB = 23.1 MB
    const size_t opart_bytes = (size_t)128 * NCHNK * 4 * 16 * 64 * 4;

    char* ws = (char*)d_ws;
    ushort_t* wT_hi  = (ushort_t*)(ws);                    // 384 KB
    ushort_t* wT_lo  = (ushort_t*)(ws + 393216);           // 384 KB
    ushort_t* woT_hi = (ushort_t*)(ws + 786432);           // 128 KB
    ushort_t* woT_lo = (ushort_t*)(ws + 917504);           // 128 KB -> 1 MB
    ushort_t* q_hi   = (ushort_t*)(ws + (1u << 20));
    ushort_t* q_lo   = (ushort_t*)(ws + (2u << 20));
    ushort_t* k_hi   = (ushort_t*)(ws + (3u << 20));
    ushort_t* k_lo   = (ushort_t*)(ws + (4u << 20));
    ushort_t* vT     = (ushort_t*)(ws + (5u << 20));       // -> 6 MB
    // x_hi/x_lo [6MB..38MB) are consumed by qkv BEFORE attn writes
    // Opart/MLpart (same region) -> temporal overlap is safe (in-order stream).
    ushort_t* x_hi   = (ushort_t*)(ws + (6u << 20));       // 16 MB
    ushort_t* x_lo   = (ushort_t*)(ws + (22u << 20));      // 16 MB -> 38 MB
    float*    Opart  = (float*)(ws + (6u << 20));          // 23.1 MB (after qkv)
    float*    MLpart = (float*)(ws + (6u << 20) + opart_bytes);  // 721 KB
    // ao (merged, normalized bf16 hi/lo, 1 MB each) overlays the dead q_hi /
    // q_lo regions (q consumed by attn; in-order stream -> safe).
    ushort_t* aoh    = (ushort_t*)(ws + (1u << 20));
    ushort_t* aol    = (ushort_t*)(ws + (2u << 20));

    prep_kernel<<<5120, 256, 0, stream>>>(w_qkv, w_out, x, wT_hi, wT_lo,
                                          woT_hi, woT_lo, x_hi, x_lo);
    qkv_kernel<<<256, 256, 0, stream>>>(x_hi, x_lo, wT_hi, wT_lo, b_qkv,
                                        q_hi, q_lo, k_hi, k_lo, vT);
    attn_kernel<<<ACTB + 128 * NCHNK, 256, 0, stream>>>(q_hi, q_lo, k_hi, k_lo, vT,
                                                        Opart, MLpart, causal);
    merge_kernel<<<2048, 256, 0, stream>>>(Opart, MLpart, aoh, aol, causal);
    proj_kernel<<<2048, 256, 0, stream>>>(aoh, aol, woT_hi, woT_lo, b_out, out);
}